// Round 2
// baseline (116.832 us; speedup 1.0000x reference)
//
#include <hip/hip_runtime.h>
#include <math.h>

typedef unsigned short u16;
typedef unsigned int u32;
typedef unsigned long long u64;
typedef __bf16 bf16x8 __attribute__((ext_vector_type(8)));
typedef short s16x4 __attribute__((ext_vector_type(4)));
typedef float f32x4 __attribute__((ext_vector_type(4)));

#define SCALING 0.17677669529663687f   // 32^-0.5
#define LOG2E 1.44269504088896f
#define LOG2_10000 13.287712379549449f

__device__ __forceinline__ u16 f2bf(float f) {
    u32 u; __builtin_memcpy(&u, &f, 4);
    u = u + 0x7FFFu + ((u >> 16) & 1u);
    return (u16)(u >> 16);
}
__device__ __forceinline__ u32 fbits(float f) {
    u32 u; __builtin_memcpy(&u, &f, 4); return u;
}
// pack two f32 -> (bf16(lo) | bf16(hi)<<16)
__device__ __forceinline__ u32 pack_bf16(float lo, float hi) {
#if __has_builtin(__builtin_amdgcn_cvt_pk_bf16_f32)
    typedef __bf16 bf16x2_t __attribute__((ext_vector_type(2)));
    bf16x2_t r = __builtin_amdgcn_cvt_pk_bf16_f32(lo, hi);
    u32 u; __builtin_memcpy(&u, &r, 4); return u;
#else
    return __builtin_amdgcn_perm(fbits(hi) + 0x8000u, fbits(lo) + 0x8000u, 0x07060302u);
#endif
}
__device__ __forceinline__ f32x4 mfma16(bf16x8 a, bf16x8 b, f32x4 c) {
    return __builtin_amdgcn_mfma_f32_16x16x32_bf16(a, b, c, 0, 0, 0);
}
// K=16 bf16 MFMA: 4 bf16 per lane per operand (2 VGPRs)
__device__ __forceinline__ f32x4 mfma_k16(u64 a, u64 b, f32x4 c) {
#if __has_builtin(__builtin_amdgcn_mfma_f32_16x16x16bf16_1k)
    s16x4 av, bv;
    __builtin_memcpy(&av, &a, 8); __builtin_memcpy(&bv, &b, 8);
    return __builtin_amdgcn_mfma_f32_16x16x16bf16_1k(av, bv, c, 0, 0, 0);
#elif __has_builtin(__builtin_amdgcn_mfma_f32_16x16x16_bf16)
    typedef __bf16 bf16x4_t __attribute__((ext_vector_type(4)));
    bf16x4_t av, bv;
    __builtin_memcpy(&av, &a, 8); __builtin_memcpy(&bv, &b, 8);
    return __builtin_amdgcn_mfma_f32_16x16x16_bf16(av, bv, c, 0, 0, 0);
#else
    f32x4 d = c;
    asm volatile("v_mfma_f32_16x16x16_bf16 %0, %1, %2, %0\n\ts_nop 4"
                 : "+v"(d) : "v"(a), "v"(b));
    return d;
#endif
}
__device__ __forceinline__ float decay_l2(int h) {
    return logf(1.0f - exp2f(-2.0f - 0.625f * (float)h)) * LOG2E;
}

// ---- prep: x->bf16 (1024 blk), W->bf16 (128 blk), theta table (128 blk) ------
__global__ __launch_bounds__(256) void prep_kernel(
    const float* __restrict__ x,
    const float* __restrict__ Wq, const float* __restrict__ Wk,
    const float* __restrict__ Wv, const float* __restrict__ Wo,
    u16* __restrict__ xb, u16* __restrict__ wb, float2* __restrict__ tc) {
    int bid = blockIdx.x;
    if (bid >= 1152) {   // tc[l*32+d] = (cos, d odd? sin : -sin)
        int idx = (bid - 1152) * 256 + threadIdx.x;   // 0..32767
        int l = idx >> 5, d = idx & 31;
        float ang = exp2f(-LOG2_10000 * (1.0f / 15.0f) * (float)(d >> 1));
        float idl = (float)((l >> 5) + (l & 31));
        float sv, cv;
        __sincosf(idl * ang, &sv, &cv);
        tc[idx] = make_float2(cv, (d & 1) ? sv : -sv);
        return;
    }
    const float* src; u16* dst; int off;
    if (bid < 1024) { src = x; dst = xb; off = bid * 2048; }
    else {
        int wsel = (bid - 1024) >> 5;
        src = (wsel == 0) ? Wq : (wsel == 1) ? Wk : (wsel == 2) ? Wv : Wo;
        dst = wb + wsel * 65536;
        off = ((bid - 1024) & 31) * 2048;
    }
    int i = off + threadIdx.x * 8;
    float4 a = *(const float4*)&src[i];
    float4 b = *(const float4*)&src[i + 4];
    int4 t;
    t.x = (int)pack_bf16(a.x, a.y); t.y = (int)pack_bf16(a.z, a.w);
    t.z = (int)pack_bf16(b.x, b.y); t.w = (int)pack_bf16(b.z, b.w);
    *(int4*)&dst[i] = t;
}

// ------- GEMM C[i][e] = sum_j A[i][j] W[e][j], MT m-frags per wave ------------
// modes: 0=q (theta-shift), 1=k (scale+shift), 2=v, 3=plain f32 out
template<int MT>
__global__ __launch_bounds__(256) void gemm_bt_kernel(
    const u16* __restrict__ A, const u16* __restrict__ Wb,
    const float2* __restrict__ tc,
    u16* __restrict__ O0, u16* __restrict__ O1, u16* __restrict__ O2,
    float* __restrict__ Of, int mode_base) {
    __shared__ __align__(16) u16 As[64 * MT * 136];
    __shared__ __align__(16) u16 Ws[64 * 136];
    int z = blockIdx.z;
    const u16* W = Wb + z * 65536;
    u16* O = (z == 0) ? O0 : (z == 1) ? O1 : O2;
    int mode = mode_base + z;
    int n0 = blockIdx.x * 64, r0 = blockIdx.y * (64 * MT);
    int tid = threadIdx.x;
    int w = tid >> 6, lane = tid & 63, ln = lane & 15, quad = lane >> 4;
    f32x4 acc[MT][4] = {};
#pragma unroll
    for (int ch = 0; ch < 2; ch++) {
        int k0 = ch * 128;
        if (ch) __syncthreads();
#pragma unroll
        for (int i = 0; i < 4 * MT; i++) {
            int c = tid + i * 256;
            int row = c >> 4, seg = c & 15;
            *(int4*)&As[row * 136 + seg * 8] = *(const int4*)&A[(long)(r0 + row) * 256 + k0 + seg * 8];
        }
#pragma unroll
        for (int i = 0; i < 4; i++) {
            int c = tid + i * 256;
            int row = c >> 4, seg = c & 15;
            *(int4*)&Ws[row * 136 + seg * 8] = *(const int4*)&W[(long)(n0 + row) * 256 + k0 + seg * 8];
        }
        __syncthreads();
#pragma unroll
        for (int kt = 0; kt < 4; kt++) {
            bf16x8 a[MT];
#pragma unroll
            for (int m = 0; m < MT; m++)
                a[m] = *(const bf16x8*)&As[(w * MT * 16 + m * 16 + ln) * 136 + kt * 32 + quad * 8];
#pragma unroll
            for (int nt = 0; nt < 4; nt++) {
                bf16x8 b = *(const bf16x8*)&Ws[(nt * 16 + ln) * 136 + kt * 32 + quad * 8];
#pragma unroll
                for (int m = 0; m < MT; m++)
                    acc[m][nt] = mfma16(a[m], b, acc[m][nt]);
            }
        }
    }
#pragma unroll
    for (int m = 0; m < MT; m++) {
        int rowg = r0 + w * MT * 16 + m * 16 + quad * 4;   // C row = quad*4 + reg
        if (mode == 3) {
#pragma unroll
            for (int nt = 0; nt < 4; nt++) {
                int e = n0 + nt * 16 + ln;
#pragma unroll
                for (int r = 0; r < 4; r++)
                    Of[(long)(rowg + r) * 256 + e] = acc[m][nt][r];
            }
            continue;
        }
        float scl = (mode == 1) ? SCALING : 1.0f;
#pragma unroll
        for (int nt = 0; nt < 4; nt++) {
            int e = n0 + nt * 16 + ln;
            int d = e & 31, hh = e >> 5;
#pragma unroll
            for (int r = 0; r < 4; r++) {
                int gi = rowg + r;
                int b = gi >> 10, l = gi & 1023;
                float v = acc[m][nt][r] * scl;
                float p = __shfl_xor(v, 1);   // partner col e^1, same row
                float res;
                if (mode == 2) {
                    res = v;
                } else {
                    float2 sc = tc[l * 32 + d];
                    res = v * sc.x + p * sc.y;
                }
                O[(((long)(b * 8 + hh)) * 1024 + l) * 32 + d] = f2bf(res);
            }
        }
    }
}

// ---- fused retention + LN + GELU: 256-q tile, 2 Q-frags/wave -----------------
// Each wave owns 32 q rows (two 16-row MFMA B-frags in one 32-row band, so
// q1i and the a0/a1 decay factors are shared). K-side LDS reads (ak/av0/av1)
// and all K/V staging now feed 2x the MFMA work; K/V staging redundancy per
// (b,h) drops 8x -> 4x. XCD-aware remap co-locates the 4 sibling q-tiles of
// one (b,h) on a single XCD so K/V stays in that XCD's L2.
__global__ __launch_bounds__(512) void attn_kernel(
    const u16* __restrict__ qr, const u16* __restrict__ kr, const u16* __restrict__ vr,
    const float* __restrict__ lng, const float* __restrict__ lnb,
    u16* __restrict__ out) {
    __shared__ __align__(16) u16 Qs[256 * 40];      // 20480 B
    __shared__ __align__(16) u16 Ks[2][64 * 40];    // 10240 B
    __shared__ __align__(16) u32 VtW[2][32 * 36];   // V^T packed dwords, 9216 B
    __shared__ float Tt[64];
    __shared__ float Ss[32];
    // remap: dispatch position p -> (bh, q-tile) with all 4 q-tiles of a bh
    // at positions == same value mod 8 (same XCD under round-robin dispatch)
    int p = blockIdx.x + 4 * (blockIdx.y + 8 * blockIdx.z);
    int xcd = p & 7, slot = p >> 3;          // slot in [0,32)
    int c = xcd * 8 + (slot >> 2);           // bh in [0,64)
    int b = c >> 3, h = c & 7, q0 = (slot & 3) * 256;
    int tid = threadIdx.x, w = tid >> 6, lane = tid & 63, ln = lane & 15, quad = lane >> 4;
    long bh = b * 8 + h;
    const u16* qb = qr + bh * 32768;
    const u16* kb = kr + bh * 32768;
    const u16* vb = vr + bh * 32768;
    float dec = decay_l2(h);
#pragma unroll
    for (int i = 0; i < 2; i++) {   // stage Q (256 rows, 512 threads x2)
        int cc = tid + i * 512;
        int row = cc >> 2, seg = cc & 3;
        *(int4*)&Qs[row * 40 + seg * 8] = *(const int4*)&qb[(q0 + row) * 32 + seg * 8];
    }
    if (tid < 63) Tt[tid] = exp2f(dec * (float)tid);
    // staging duties: waves 0-3 stage K, waves 4-7 stage V
    bool isK = (tid < 256);
    int krow = (tid & 255) >> 2, kseg = tid & 3;
    int vt = tid & 255, vp = vt >> 3, vseg = vt & 7;
    int4 kreg; int2 v0, v1;
    if (isK) {
        kreg = *(const int4*)&kb[(long)krow * 32 + kseg * 8];
    } else {
        v0 = *(const int2*)&vb[(long)(vp * 2) * 32 + vseg * 4];
        v1 = *(const int2*)&vb[(long)(vp * 2 + 1) * 32 + vseg * 4];
    }
    __syncthreads();   // Qs + Tt ready
    bf16x8 aq0 = *(const bf16x8*)&Qs[(w * 32 + ln) * 40 + quad * 8];
    bf16x8 aq1 = *(const bf16x8*)&Qs[(w * 32 + 16 + ln) * 40 + quad * 8];
    int qA = q0 + w * 32 + ln;               // u=0 q row; u=1 is qA+16
    int q1i = qA >> 5;                       // same for both frags (32-row band)
    int q2i0 = qA & 31, q2i1 = (qA + 16) & 31;
    if (tid < 32) {
        float s = 0.0f;
#pragma unroll
        for (int b2 = 0; b2 < 32; b2++) s += Tt[abs(tid - b2)];
        Ss[tid] = s;
    }
    // write tile 0 to buf 0 (tile 1 is loaded at the top of iteration kt=0)
    if (isK) {
        *(int4*)&Ks[0][krow * 40 + kseg * 8] = kreg;
    } else {
        VtW[0][(vseg * 4 + 0) * 36 + vp] = __builtin_amdgcn_perm(v1.x, v0.x, 0x05040100u);
        VtW[0][(vseg * 4 + 1) * 36 + vp] = __builtin_amdgcn_perm(v1.x, v0.x, 0x07060302u);
        VtW[0][(vseg * 4 + 2) * 36 + vp] = __builtin_amdgcn_perm(v1.y, v0.y, 0x05040100u);
        VtW[0][(vseg * 4 + 3) * 36 + vp] = __builtin_amdgcn_perm(v1.y, v0.y, 0x07060302u);
    }
    __syncthreads();   // Ss + buf0 ready
    float rqv0 = rsqrtf(Ss[q1i] * Ss[q2i0]);
    float rqv1 = rsqrtf(Ss[q1i] * Ss[q2i1]);
    float bt[2][2][4];                       // [u][s2][r], rqv folded
#pragma unroll
    for (int s2 = 0; s2 < 2; s2++)
#pragma unroll
        for (int r = 0; r < 4; r++) {
            int kk = s2 * 16 + quad * 4 + r;
            bt[0][s2][r] = Tt[abs(q2i0 - kk)] * rqv0;
            bt[1][s2][r] = Tt[abs(q2i1 - kk)] * rqv1;
        }
    f32x4 accO[2][2] = {};                   // [u][d-half]
    float den[2] = {0.0f, 0.0f};
    for (int kt = 0; kt < 16; kt++) {
        int cur = kt & 1;
        // top-issue prefetch of tile kt+1: whole compute phase covers the latency
        if (kt < 15) {
            long t1 = (long)(kt + 1) * 64;
            if (isK) {
                kreg = *(const int4*)&kb[(t1 + krow) * 32 + kseg * 8];
            } else {
                v0 = *(const int2*)&vb[(t1 + vp * 2) * 32 + vseg * 4];
                v1 = *(const int2*)&vb[(t1 + vp * 2 + 1) * 32 + vseg * 4];
            }
        }
        float a0 = Tt[abs(q1i - 2 * kt)];
        float a1 = Tt[abs(q1i - 2 * kt - 1)];
        const u16* ksb = &Ks[cur][0];
        const u32* vtb = &VtW[cur][0];
#pragma unroll
        for (int nt = 0; nt < 4; nt++) {
            bf16x8 ak = *(const bf16x8*)&ksb[(nt * 16 + ln) * 40 + quad * 8];
            f32x4 s0 = mfma16(ak, aq0, (f32x4){0.f, 0.f, 0.f, 0.f});   // S^T rows kk, col qA
            f32x4 s1 = mfma16(ak, aq1, (f32x4){0.f, 0.f, 0.f, 0.f});   // col qA+16
            float aa = (nt & 2) ? a1 : a0;
            u64 av0 = *(const u64*)&vtb[ln * 36 + nt * 8 + quad * 2];         // shared by u
            u64 av1 = *(const u64*)&vtb[(16 + ln) * 36 + nt * 8 + quad * 2];
#pragma unroll
            for (int u = 0; u < 2; u++) {
                f32x4 s = u ? s1 : s0;
                float p0 = s[0] * aa * bt[u][nt & 1][0];
                float p1 = s[1] * aa * bt[u][nt & 1][1];
                float p2 = s[2] * aa * bt[u][nt & 1][2];
                float p3 = s[3] * aa * bt[u][nt & 1][3];
                den[u] += fabsf(p0); den[u] += fabsf(p1);
                den[u] += fabsf(p2); den[u] += fabsf(p3);
                // P^T fragment stays in registers: B-frag of K=16 MFMA = C-layout
                u32 blo = pack_bf16(p0, p1), bhi = pack_bf16(p2, p3);
                u64 bb = ((u64)bhi << 32) | blo;
                accO[u][0] = mfma_k16(av0, bb, accO[u][0]);   // O^T rows d=quad*4+r
                accO[u][1] = mfma_k16(av1, bb, accO[u][1]);   // d = 16 + quad*4+r
            }
        }
        if (kt < 15) {
            int nb = 1 - cur;
            if (isK) {
                *(int4*)&Ks[nb][krow * 40 + kseg * 8] = kreg;
            } else {
                VtW[nb][(vseg * 4 + 0) * 36 + vp] = __builtin_amdgcn_perm(v1.x, v0.x, 0x05040100u);
                VtW[nb][(vseg * 4 + 1) * 36 + vp] = __builtin_amdgcn_perm(v1.x, v0.x, 0x07060302u);
                VtW[nb][(vseg * 4 + 2) * 36 + vp] = __builtin_amdgcn_perm(v1.y, v0.y, 0x05040100u);
                VtW[nb][(vseg * 4 + 3) * 36 + vp] = __builtin_amdgcn_perm(v1.y, v0.y, 0x07060302u);
            }
            __syncthreads();
        }
    }
    // epilogue per q-frag: den reduce over quads, LN over d, GELU, store
#pragma unroll
    for (int u = 0; u < 2; u++) {
        float dn = den[u];
        dn += __shfl_xor(dn, 16);
        dn += __shfl_xor(dn, 32);
        float id = 1.0f / fminf(fmaxf(dn, 1.0f), 50000.0f);
        float o[8];
#pragma unroll
        for (int r = 0; r < 4; r++) { o[r] = accO[u][0][r] * id; o[4 + r] = accO[u][1][r] * id; }
        float s1 = 0.0f, s2 = 0.0f;
#pragma unroll
        for (int i = 0; i < 8; i++) { s1 += o[i]; s2 += o[i] * o[i]; }
        s1 += __shfl_xor(s1, 16); s1 += __shfl_xor(s1, 32);
        s2 += __shfl_xor(s2, 16); s2 += __shfl_xor(s2, 32);
        float mean = s1 * (1.0f / 32.0f);
        float var = s2 * (1.0f / 32.0f) - mean * mean;
        float rstd = rsqrtf(var + 1e-5f);
        float xg[8];
#pragma unroll
        for (int nv = 0; nv < 2; nv++)
#pragma unroll
            for (int r = 0; r < 4; r++) {
                int d = nv * 16 + quad * 4 + r;
                float xv = (o[nv * 4 + r] - mean) * rstd * lng[d] + lnb[d];
                xg[nv * 4 + r] = 0.5f * xv * (1.0f + erff(xv * 0.70710678118654752f));
            }
        int q = qA + u * 16;
        u16* orow = out + ((long)(b * 1024 + q)) * 256 + h * 32;
        int2 st0, st1;
        st0.x = (int)pack_bf16(xg[0], xg[1]); st0.y = (int)pack_bf16(xg[2], xg[3]);
        st1.x = (int)pack_bf16(xg[4], xg[5]); st1.y = (int)pack_bf16(xg[6], xg[7]);
        *(int2*)&orow[quad * 4] = st0;
        *(int2*)&orow[16 + quad * 4] = st1;
    }
}

extern "C" void kernel_launch(void* const* d_in, const int* in_sizes, int n_in,
                              void* d_out, int out_size, void* d_ws, size_t ws_size,
                              hipStream_t stream) {
    const float* x   = (const float*)d_in[0];
    const float* Wq  = (const float*)d_in[1];
    const float* Wk  = (const float*)d_in[2];
    const float* Wv  = (const float*)d_in[3];
    const float* Wo  = (const float*)d_in[4];
    const float* lng = (const float*)d_in[5];
    const float* lnb = (const float*)d_in[6];
    float* outp = (float*)d_out;

    u16* xb    = (u16*)d_ws;            // [B*L][256] bf16, 4 MB
    u16* wb    = xb + 2097152;          // Wq|Wk|Wv|Wo bf16, 0.5 MB
    u16* qr    = wb + 262144;           // [B][H][L][32] bf16, 4 MB
    u16* kr    = qr + 2097152;
    u16* vr    = kr + 2097152;
    u16* attnb = vr + 2097152;          // [B*L][256] bf16, 4 MB
    float2* tc = (float2*)(attnb + 2097152);   // [L][32], 256 KB

    prep_kernel<<<1280, 256, 0, stream>>>(x, Wq, Wk, Wv, Wo, xb, wb, tc);
    // MT=2: 128-row tiles, 768 blocks = 3/CU (52 KB LDS), 2x MFMA per wave
    gemm_bt_kernel<2><<<dim3(4, 64, 3), 256, 0, stream>>>(xb, wb, tc, qr, kr, vr, nullptr, 0);
    attn_kernel<<<dim3(4, 8, 8), 512, 0, stream>>>(qr, kr, vr, lng, lnb, attnb);
    gemm_bt_kernel<1><<<dim3(4, 128, 1), 256, 0, stream>>>(attnb, wb + 3 * 65536, tc, nullptr, nullptr, nullptr, outp, 3);
}

// Round 3
// 115.562 us; speedup vs baseline: 1.0110x; 1.0110x over previous
//
#include <hip/hip_runtime.h>
#include <math.h>

typedef unsigned short u16;
typedef unsigned int u32;
typedef unsigned long long u64;
typedef __bf16 bf16x8 __attribute__((ext_vector_type(8)));
typedef short s16x4 __attribute__((ext_vector_type(4)));
typedef float f32x4 __attribute__((ext_vector_type(4)));
typedef u32 u32x4 __attribute__((ext_vector_type(4)));

#define SCALING 0.17677669529663687f   // 32^-0.5
#define LOG2E 1.44269504088896f
#define LOG2_10000 13.287712379549449f

__device__ __forceinline__ u16 f2bf(float f) {
    u32 u; __builtin_memcpy(&u, &f, 4);
    u = u + 0x7FFFu + ((u >> 16) & 1u);
    return (u16)(u >> 16);
}
__device__ __forceinline__ u32 fbits(float f) {
    u32 u; __builtin_memcpy(&u, &f, 4); return u;
}
// pack two f32 -> (bf16(lo) | bf16(hi)<<16)
__device__ __forceinline__ u32 pack_bf16(float lo, float hi) {
#if __has_builtin(__builtin_amdgcn_cvt_pk_bf16_f32)
    typedef __bf16 bf16x2_t __attribute__((ext_vector_type(2)));
    bf16x2_t r = __builtin_amdgcn_cvt_pk_bf16_f32(lo, hi);
    u32 u; __builtin_memcpy(&u, &r, 4); return u;
#else
    return __builtin_amdgcn_perm(fbits(hi) + 0x8000u, fbits(lo) + 0x8000u, 0x07060302u);
#endif
}
__device__ __forceinline__ f32x4 mfma16(bf16x8 a, bf16x8 b, f32x4 c) {
    return __builtin_amdgcn_mfma_f32_16x16x32_bf16(a, b, c, 0, 0, 0);
}
// K=16 bf16 MFMA: 4 bf16 per lane per operand (2 VGPRs)
__device__ __forceinline__ f32x4 mfma_k16(u64 a, u64 b, f32x4 c) {
#if __has_builtin(__builtin_amdgcn_mfma_f32_16x16x16bf16_1k)
    s16x4 av, bv;
    __builtin_memcpy(&av, &a, 8); __builtin_memcpy(&bv, &b, 8);
    return __builtin_amdgcn_mfma_f32_16x16x16bf16_1k(av, bv, c, 0, 0, 0);
#elif __has_builtin(__builtin_amdgcn_mfma_f32_16x16x16_bf16)
    typedef __bf16 bf16x4_t __attribute__((ext_vector_type(4)));
    bf16x4_t av, bv;
    __builtin_memcpy(&av, &a, 8); __builtin_memcpy(&bv, &b, 8);
    return __builtin_amdgcn_mfma_f32_16x16x16_bf16(av, bv, c, 0, 0, 0);
#else
    f32x4 d = c;
    asm volatile("v_mfma_f32_16x16x16_bf16 %0, %1, %2, %0\n\ts_nop 4"
                 : "+v"(d) : "v"(a), "v"(b));
    return d;
#endif
}
__device__ __forceinline__ float decay_l2(int h) {
    return logf(1.0f - exp2f(-2.0f - 0.625f * (float)h)) * LOG2E;
}

// ---- prep: x->bf16 (1024 blk), W->bf16 (128 blk), theta table (128 blk) ------
__global__ __launch_bounds__(256) void prep_kernel(
    const float* __restrict__ x,
    const float* __restrict__ Wq, const float* __restrict__ Wk,
    const float* __restrict__ Wv, const float* __restrict__ Wo,
    u16* __restrict__ xb, u16* __restrict__ wb, float2* __restrict__ tc) {
    int bid = blockIdx.x;
    if (bid >= 1152) {   // tc[l*32+d] = (cos, d odd? sin : -sin)
        int idx = (bid - 1152) * 256 + threadIdx.x;   // 0..32767
        int l = idx >> 5, d = idx & 31;
        float ang = exp2f(-LOG2_10000 * (1.0f / 15.0f) * (float)(d >> 1));
        float idl = (float)((l >> 5) + (l & 31));
        float sv, cv;
        __sincosf(idl * ang, &sv, &cv);
        tc[idx] = make_float2(cv, (d & 1) ? sv : -sv);
        return;
    }
    const float* src; u16* dst; int off;
    if (bid < 1024) { src = x; dst = xb; off = bid * 2048; }
    else {
        int wsel = (bid - 1024) >> 5;
        src = (wsel == 0) ? Wq : (wsel == 1) ? Wk : (wsel == 2) ? Wv : Wo;
        dst = wb + wsel * 65536;
        off = ((bid - 1024) & 31) * 2048;
    }
    int i = off + threadIdx.x * 8;
    float4 a = *(const float4*)&src[i];
    float4 b = *(const float4*)&src[i + 4];
    int4 t;
    t.x = (int)pack_bf16(a.x, a.y); t.y = (int)pack_bf16(a.z, a.w);
    t.z = (int)pack_bf16(b.x, b.y); t.w = (int)pack_bf16(b.z, b.w);
    *(int4*)&dst[i] = t;
}

// ------- GEMM C[i][e] = sum_j A[i][j] W[e][j], MT m-frags per wave ------------
// modes: 0=q (theta-shift), 1=k (scale+shift), 2=v, 3=plain f32 out
template<int MT>
__global__ __launch_bounds__(256) void gemm_bt_kernel(
    const u16* __restrict__ A, const u16* __restrict__ Wb,
    const float2* __restrict__ tc,
    u16* __restrict__ O0, u16* __restrict__ O1, u16* __restrict__ O2,
    float* __restrict__ Of, int mode_base) {
    __shared__ __align__(16) u16 As[64 * MT * 136];
    __shared__ __align__(16) u16 Ws[64 * 136];
    int z = blockIdx.z;
    const u16* W = Wb + z * 65536;
    u16* O = (z == 0) ? O0 : (z == 1) ? O1 : O2;
    int mode = mode_base + z;
    int n0 = blockIdx.x * 64, r0 = blockIdx.y * (64 * MT);
    int tid = threadIdx.x;
    int w = tid >> 6, lane = tid & 63, ln = lane & 15, quad = lane >> 4;
    f32x4 acc[MT][4] = {};
#pragma unroll
    for (int ch = 0; ch < 2; ch++) {
        int k0 = ch * 128;
        if (ch) __syncthreads();
#pragma unroll
        for (int i = 0; i < 4 * MT; i++) {
            int c = tid + i * 256;
            int row = c >> 4, seg = c & 15;
            *(int4*)&As[row * 136 + seg * 8] = *(const int4*)&A[(long)(r0 + row) * 256 + k0 + seg * 8];
        }
#pragma unroll
        for (int i = 0; i < 4; i++) {
            int c = tid + i * 256;
            int row = c >> 4, seg = c & 15;
            *(int4*)&Ws[row * 136 + seg * 8] = *(const int4*)&W[(long)(n0 + row) * 256 + k0 + seg * 8];
        }
        __syncthreads();
#pragma unroll
        for (int kt = 0; kt < 4; kt++) {
            bf16x8 a[MT];
#pragma unroll
            for (int m = 0; m < MT; m++)
                a[m] = *(const bf16x8*)&As[(w * MT * 16 + m * 16 + ln) * 136 + kt * 32 + quad * 8];
#pragma unroll
            for (int nt = 0; nt < 4; nt++) {
                bf16x8 b = *(const bf16x8*)&Ws[(nt * 16 + ln) * 136 + kt * 32 + quad * 8];
#pragma unroll
                for (int m = 0; m < MT; m++)
                    acc[m][nt] = mfma16(a[m], b, acc[m][nt]);
            }
        }
    }
#pragma unroll
    for (int m = 0; m < MT; m++) {
        int rowg = r0 + w * MT * 16 + m * 16 + quad * 4;   // C row = quad*4 + reg
        if (mode == 3) {
#pragma unroll
            for (int nt = 0; nt < 4; nt++) {
                int e = n0 + nt * 16 + ln;
#pragma unroll
                for (int r = 0; r < 4; r++)
                    Of[(long)(rowg + r) * 256 + e] = acc[m][nt][r];
            }
            continue;
        }
        float scl = (mode == 1) ? SCALING : 1.0f;
#pragma unroll
        for (int nt = 0; nt < 4; nt++) {
            int e = n0 + nt * 16 + ln;
            int d = e & 31, hh = e >> 5;
#pragma unroll
            for (int r = 0; r < 4; r++) {
                int gi = rowg + r;
                int b = gi >> 10, l = gi & 1023;
                float v = acc[m][nt][r] * scl;
                float p = __shfl_xor(v, 1);   // partner col e^1, same row
                float res;
                if (mode == 2) {
                    res = v;
                } else {
                    float2 sc = tc[l * 32 + d];
                    res = v * sc.x + p * sc.y;
                }
                O[(((long)(b * 8 + hh)) * 1024 + l) * 32 + d] = f2bf(res);
            }
        }
    }
}

// ---- fused retention + LN + GELU: 128-q tile, 4 waves, 2 Q-frags/wave --------
// vs R0: 256 threads instead of 512, each wave owns 32 q rows (two 16-row
// B-frags in one 32-row band -> q1i/a0/a1 shared). Every K-side LDS read
// (ak + av) now feeds 2x the MFMA work, halving per-CU LDS-pipe pressure
// while keeping 512 blocks = 2 blocks/CU residency. V^T LDS layout is
// interleaved (d, d+16 pairs adjacent) so av0+av1 come from ONE aligned
// ds_read_b128 instead of two ds_read_b64.
__global__ __launch_bounds__(256) void attn_kernel(
    const u16* __restrict__ qr, const u16* __restrict__ kr, const u16* __restrict__ vr,
    const float* __restrict__ lng, const float* __restrict__ lnb,
    u16* __restrict__ out) {
    __shared__ __align__(16) u16 Qs[128 * 40];      // 10240 B
    __shared__ __align__(16) u16 Ks[2][64 * 40];    // 10240 B
    __shared__ __align__(16) u32 VtW[2][16 * 68];   // V^T interleaved, 8704 B
    __shared__ float Tt[64];
    __shared__ float Ss[32];
    int b = blockIdx.z, h = blockIdx.y, q0 = blockIdx.x * 128;
    int tid = threadIdx.x, w = tid >> 6, lane = tid & 63, ln = lane & 15, quad = lane >> 4;
    long bh = b * 8 + h;
    const u16* qb = qr + bh * 32768;
    const u16* kb = kr + bh * 32768;
    const u16* vb = vr + bh * 32768;
    float dec = decay_l2(h);
#pragma unroll
    for (int i = 0; i < 2; i++) {   // stage Q (128 rows, 256 threads x2)
        int cc = tid + i * 256;
        int row = cc >> 2, seg = cc & 3;
        *(int4*)&Qs[row * 40 + seg * 8] = *(const int4*)&qb[(q0 + row) * 32 + seg * 8];
    }
    if (tid < 63) Tt[tid] = exp2f(dec * (float)tid);
    // staging: every thread loads one K int4 and one V row-pair (2x int2)
    int krow = tid >> 2, kseg = tid & 3;        // K rows 0..63
    int vp = tid >> 3, vseg = tid & 7;          // V pair 0..31, dim-seg 0..7
    int vrow = (vseg & 3) * 4;                  // VtW row base (d & 15)
    int vcol = (vp >> 1) * 4 + (vp & 1) + (vseg >> 2) * 2;
    int4 kreg; int2 v0, v1;
    kreg = *(const int4*)&kb[(long)krow * 32 + kseg * 8];
    v0 = *(const int2*)&vb[(long)(vp * 2) * 32 + vseg * 4];
    v1 = *(const int2*)&vb[(long)(vp * 2 + 1) * 32 + vseg * 4];
    __syncthreads();   // Qs + Tt ready
    bf16x8 aq0 = *(const bf16x8*)&Qs[(w * 32 + ln) * 40 + quad * 8];
    bf16x8 aq1 = *(const bf16x8*)&Qs[(w * 32 + 16 + ln) * 40 + quad * 8];
    int qA = q0 + w * 32 + ln;               // u=0 q row; u=1 is qA+16
    int q1i = qA >> 5;                       // shared by both frags (32-row band)
    int q2i0 = qA & 31, q2i1 = (qA + 16) & 31;
    if (tid < 32) {
        float s = 0.0f;
#pragma unroll
        for (int b2 = 0; b2 < 32; b2++) s += Tt[abs(tid - b2)];
        Ss[tid] = s;
    }
    // write tile 0 to buf 0 (tile 1 is loaded at the top of iteration kt=0)
    *(int4*)&Ks[0][krow * 40 + kseg * 8] = kreg;
    {
        u32* vwb = &VtW[0][0];
        vwb[(vrow + 0) * 68 + vcol] = __builtin_amdgcn_perm(v1.x, v0.x, 0x05040100u);
        vwb[(vrow + 1) * 68 + vcol] = __builtin_amdgcn_perm(v1.x, v0.x, 0x07060302u);
        vwb[(vrow + 2) * 68 + vcol] = __builtin_amdgcn_perm(v1.y, v0.y, 0x05040100u);
        vwb[(vrow + 3) * 68 + vcol] = __builtin_amdgcn_perm(v1.y, v0.y, 0x07060302u);
    }
    __syncthreads();   // Ss + buf0 ready
    float rqv0 = rsqrtf(Ss[q1i] * Ss[q2i0]);
    float rqv1 = rsqrtf(Ss[q1i] * Ss[q2i1]);
    float bt[2][2][4];                       // [u][s2][r], rqv folded
#pragma unroll
    for (int s2 = 0; s2 < 2; s2++)
#pragma unroll
        for (int r = 0; r < 4; r++) {
            int kk = s2 * 16 + quad * 4 + r;
            bt[0][s2][r] = Tt[abs(q2i0 - kk)] * rqv0;
            bt[1][s2][r] = Tt[abs(q2i1 - kk)] * rqv1;
        }
    f32x4 accO[2][2] = {};                   // [u][d-half]
    float den[2] = {0.0f, 0.0f};
    for (int kt = 0; kt < 16; kt++) {
        int cur = kt & 1;
        // top-issue prefetch of tile kt+1: whole compute phase covers the latency
        if (kt < 15) {
            long t1 = (long)(kt + 1) * 64;
            kreg = *(const int4*)&kb[(t1 + krow) * 32 + kseg * 8];
            v0 = *(const int2*)&vb[(t1 + vp * 2) * 32 + vseg * 4];
            v1 = *(const int2*)&vb[(t1 + vp * 2 + 1) * 32 + vseg * 4];
        }
        float a0 = Tt[abs(q1i - 2 * kt)];
        float a1 = Tt[abs(q1i - 2 * kt - 1)];
        const u16* ksb = &Ks[cur][0];
        const u32* vtb = &VtW[cur][0];
#pragma unroll
        for (int nt = 0; nt < 4; nt++) {
            bf16x8 ak = *(const bf16x8*)&ksb[(nt * 16 + ln) * 40 + quad * 8];
            f32x4 s0 = mfma16(ak, aq0, (f32x4){0.f, 0.f, 0.f, 0.f});   // S^T rows kk, col qA
            f32x4 s1 = mfma16(ak, aq1, (f32x4){0.f, 0.f, 0.f, 0.f});   // col qA+16
            float aa = (nt & 2) ? a1 : a0;
            // one b128: [av0.lo, av0.hi, av1.lo, av1.hi] (d=ln and d=ln+16)
            u32x4 vv = *(const u32x4*)&vtb[ln * 68 + (nt * 4 + quad) * 4];
            u64 av0 = ((u64)vv.y << 32) | vv.x;
            u64 av1 = ((u64)vv.w << 32) | vv.z;
#pragma unroll
            for (int u = 0; u < 2; u++) {
                f32x4 s = u ? s1 : s0;
                float p0 = s[0] * aa * bt[u][nt & 1][0];
                float p1 = s[1] * aa * bt[u][nt & 1][1];
                float p2 = s[2] * aa * bt[u][nt & 1][2];
                float p3 = s[3] * aa * bt[u][nt & 1][3];
                den[u] += fabsf(p0); den[u] += fabsf(p1);
                den[u] += fabsf(p2); den[u] += fabsf(p3);
                // P^T fragment stays in registers: B-frag of K=16 MFMA = C-layout
                u32 blo = pack_bf16(p0, p1), bhi = pack_bf16(p2, p3);
                u64 bb = ((u64)bhi << 32) | blo;
                accO[u][0] = mfma_k16(av0, bb, accO[u][0]);   // O^T rows d=quad*4+r
                accO[u][1] = mfma_k16(av1, bb, accO[u][1]);   // d = 16 + quad*4+r
            }
        }
        if (kt < 15) {
            int nb = 1 - cur;
            *(int4*)&Ks[nb][krow * 40 + kseg * 8] = kreg;
            u32* vwb = &VtW[nb][0];
            vwb[(vrow + 0) * 68 + vcol] = __builtin_amdgcn_perm(v1.x, v0.x, 0x05040100u);
            vwb[(vrow + 1) * 68 + vcol] = __builtin_amdgcn_perm(v1.x, v0.x, 0x07060302u);
            vwb[(vrow + 2) * 68 + vcol] = __builtin_amdgcn_perm(v1.y, v0.y, 0x05040100u);
            vwb[(vrow + 3) * 68 + vcol] = __builtin_amdgcn_perm(v1.y, v0.y, 0x07060302u);
            __syncthreads();
        }
    }
    // epilogue per q-frag: den reduce over quads, LN over d, GELU, store
#pragma unroll
    for (int u = 0; u < 2; u++) {
        float dn = den[u];
        dn += __shfl_xor(dn, 16);
        dn += __shfl_xor(dn, 32);
        float id = 1.0f / fminf(fmaxf(dn, 1.0f), 50000.0f);
        float o[8];
#pragma unroll
        for (int r = 0; r < 4; r++) { o[r] = accO[u][0][r] * id; o[4 + r] = accO[u][1][r] * id; }
        float s1 = 0.0f, s2 = 0.0f;
#pragma unroll
        for (int i = 0; i < 8; i++) { s1 += o[i]; s2 += o[i] * o[i]; }
        s1 += __shfl_xor(s1, 16); s1 += __shfl_xor(s1, 32);
        s2 += __shfl_xor(s2, 16); s2 += __shfl_xor(s2, 32);
        float mean = s1 * (1.0f / 32.0f);
        float var = s2 * (1.0f / 32.0f) - mean * mean;
        float rstd = rsqrtf(var + 1e-5f);
        float xg[8];
#pragma unroll
        for (int nv = 0; nv < 2; nv++)
#pragma unroll
            for (int r = 0; r < 4; r++) {
                int d = nv * 16 + quad * 4 + r;
                float xv = (o[nv * 4 + r] - mean) * rstd * lng[d] + lnb[d];
                xg[nv * 4 + r] = 0.5f * xv * (1.0f + erff(xv * 0.70710678118654752f));
            }
        int q = qA + u * 16;
        u16* orow = out + ((long)(b * 1024 + q)) * 256 + h * 32;
        int2 st0, st1;
        st0.x = (int)pack_bf16(xg[0], xg[1]); st0.y = (int)pack_bf16(xg[2], xg[3]);
        st1.x = (int)pack_bf16(xg[4], xg[5]); st1.y = (int)pack_bf16(xg[6], xg[7]);
        *(int2*)&orow[quad * 4] = st0;
        *(int2*)&orow[16 + quad * 4] = st1;
    }
}

extern "C" void kernel_launch(void* const* d_in, const int* in_sizes, int n_in,
                              void* d_out, int out_size, void* d_ws, size_t ws_size,
                              hipStream_t stream) {
    const float* x   = (const float*)d_in[0];
    const float* Wq  = (const float*)d_in[1];
    const float* Wk  = (const float*)d_in[2];
    const float* Wv  = (const float*)d_in[3];
    const float* Wo  = (const float*)d_in[4];
    const float* lng = (const float*)d_in[5];
    const float* lnb = (const float*)d_in[6];
    float* outp = (float*)d_out;

    u16* xb    = (u16*)d_ws;            // [B*L][256] bf16, 4 MB
    u16* wb    = xb + 2097152;          // Wq|Wk|Wv|Wo bf16, 0.5 MB
    u16* qr    = wb + 262144;           // [B][H][L][32] bf16, 4 MB
    u16* kr    = qr + 2097152;
    u16* vr    = kr + 2097152;
    u16* attnb = vr + 2097152;          // [B*L][256] bf16, 4 MB
    float2* tc = (float2*)(attnb + 2097152);   // [L][32], 256 KB

    prep_kernel<<<1280, 256, 0, stream>>>(x, Wq, Wk, Wv, Wo, xb, wb, tc);
    gemm_bt_kernel<1><<<dim3(4, 128, 3), 256, 0, stream>>>(xb, wb, tc, qr, kr, vr, nullptr, 0);
    attn_kernel<<<dim3(8, 8, 8), 256, 0, stream>>>(qr, kr, vr, lng, lnb, attnb);
    gemm_bt_kernel<1><<<dim3(4, 128, 1), 256, 0, stream>>>(attnb, wb + 3 * 65536, tc, nullptr, nullptr, nullptr, outp, 3);
}